// Round 1
// baseline (737.711 us; speedup 1.0000x reference)
//
#include <hip/hip_runtime.h>
#include <math.h>

// Problem constants (from reference)
#define N_NODES 100000
#define C_CL 30
#define D_IN 256
#define TILE 32
#define N_TILES (N_NODES / TILE)   // 3125 exact

// d_out float offsets: (out, mincut, ortho, Z, S) concatenated
#define OUT_MAT 0        // 30*64
#define OUT_MC 1920
#define OUT_OR 1921
#define OUT_Z 1922       // 30*256
#define OUT_S 9602       // N*30

// ws float offsets
#define WS_M 0           // 30*256  (M = S^T x)
#define WS_SS 7680       // 30*30
#define WS_CS 8580       // 30 (colsum S)
#define WS_CUT 8610      // 1
#define WS_ACC_COUNT 8611
#define WS_H1 8640       // 30*256
#define WS_H2 16320      // 30*256
#define WS_WA 24000      // 256*32 padded W_assign (16B-aligned rows)

// ---------------------------------------------------------------------------
// prep: pad W_assign to stride-32 (16B-aligned float4 rows) and zero accums
__global__ __launch_bounds__(256)
void k_prep(const float* __restrict__ Wa, float* __restrict__ ws) {
  const int b = blockIdx.x, t = threadIdx.x;
  if (b < 32) {
    const int k = b * 8 + (t >> 5);
    const int c = t & 31;
    ws[WS_WA + k * 32 + c] = (c < C_CL) ? Wa[k * C_CL + c] : 0.f;
  } else {
    for (int i = t; i < WS_ACC_COUNT; i += 256) ws[i] = 0.f;
  }
}

// ---------------------------------------------------------------------------
// Fused node pass: S = softmax(x@Wa + ba); write S; accumulate
//   M += S^T x ; SS += S^T S ; colsum += sum_rows(S)
__global__ __launch_bounds__(256, 2)
void k_assign(const float* __restrict__ x, const float* __restrict__ ba,
              float* __restrict__ S_out, float* __restrict__ ws) {
  __shared__ float xs[TILE][257];   // +1 pad: bank = (n + k) % 32
  __shared__ float st[TILE][32];    // S tile, cols 30,31 zeroed
  __shared__ float bas[C_CL];

  const int t = threadIdx.x;
  if (t < C_CL) bas[t] = ba[t];

  const float* __restrict__ wa = ws + WS_WA;   // L1/L2-resident, 32 KB

  float macc0[16], macc1[16];
  #pragma unroll
  for (int j = 0; j < 16; ++j) { macc0[j] = 0.f; macc1[j] = 0.f; }
  float ssa0 = 0.f, ssa1 = 0.f, ssa2 = 0.f, ssa3 = 0.f, csa = 0.f;

  const int ng = t >> 4, q = t & 15;       // phase S: nodes {ng, ng+16}, k-slice q
  const int h = t >> 7, cl = t & 127;      // phase M: c-half h, cols {cl, cl+128}
  const int sc1 = (t / 15) * 2, sc2 = (t % 15) * 2;  // phase SS (t<225)

  for (int tile = blockIdx.x; tile < N_TILES; tile += gridDim.x) {
    const int node0 = tile * TILE;
    __syncthreads();  // guard xs/st reuse
    // ---- stage x tile (coalesced float4) ----
    #pragma unroll
    for (int i = 0; i < 8; ++i) {
      const int g = t + 256 * i;
      const int n = g >> 6, cc = g & 63;
      const float4 v = *reinterpret_cast<const float4*>(
          x + (size_t)(node0 + n) * D_IN + cc * 4);
      float* dst = &xs[n][cc * 4];
      dst[0] = v.x; dst[1] = v.y; dst[2] = v.z; dst[3] = v.w;
    }
    __syncthreads();
    // ---- logits (2 nodes x 30 clusters per thread, k-slice q) ----
    float pl0[C_CL], pl1[C_CL];
    #pragma unroll
    for (int c = 0; c < C_CL; ++c) { pl0[c] = 0.f; pl1[c] = 0.f; }
    #pragma unroll
    for (int kk = 0; kk < 16; ++kk) {
      const int k = kk * 16 + q;
      const float xv0 = xs[ng][k];
      const float xv1 = xs[ng + 16][k];
      const float4* wrow = reinterpret_cast<const float4*>(wa + k * 32);
      #pragma unroll
      for (int cg = 0; cg < 8; ++cg) {
        const float4 w = wrow[cg];
        const int c = cg * 4;
        pl0[c] += xv0 * w.x;  pl1[c] += xv1 * w.x;
        pl0[c + 1] += xv0 * w.y;  pl1[c + 1] += xv1 * w.y;
        if (c + 2 < C_CL) { pl0[c + 2] += xv0 * w.z; pl1[c + 2] += xv1 * w.z; }
        if (c + 3 < C_CL) { pl0[c + 3] += xv0 * w.w; pl1[c + 3] += xv1 * w.w; }
      }
    }
    // ---- butterfly reduce over the 16 q-lanes (in-wave) ----
    #pragma unroll
    for (int m = 1; m <= 8; m <<= 1) {
      #pragma unroll
      for (int c = 0; c < C_CL; ++c) {
        pl0[c] += __shfl_xor(pl0[c], m, 64);
        pl1[c] += __shfl_xor(pl1[c], m, 64);
      }
    }
    // ---- softmax (redundant across q-lanes; cheap) ----
    float mx0 = -3.0e38f, mx1 = -3.0e38f;
    #pragma unroll
    for (int c = 0; c < C_CL; ++c) {
      pl0[c] += bas[c]; pl1[c] += bas[c];
      mx0 = fmaxf(mx0, pl0[c]); mx1 = fmaxf(mx1, pl1[c]);
    }
    float sm0 = 0.f, sm1 = 0.f;
    #pragma unroll
    for (int c = 0; c < C_CL; ++c) {
      pl0[c] = __expf(pl0[c] - mx0); sm0 += pl0[c];
      pl1[c] = __expf(pl1[c] - mx1); sm1 += pl1[c];
    }
    const float r0 = 1.f / sm0, r1 = 1.f / sm1;
    st[ng][q]           = pl0[q] * r0;
    st[ng][q + 16]      = (q + 16 < C_CL) ? pl0[q + 16] * r0 : 0.f;
    st[ng + 16][q]      = pl1[q] * r1;
    st[ng + 16][q + 16] = (q + 16 < C_CL) ? pl1[q + 16] * r1 : 0.f;
    __syncthreads();
    // ---- write S (coalesced-ish) ----
    #pragma unroll
    for (int i = 0; i < 4; ++i) {
      const int g = t + 256 * i;
      const int n = g >> 5, c = g & 31;
      if (c < C_CL) S_out[(size_t)(node0 + n) * C_CL + c] = st[n][c];
    }
    // ---- M += st^T @ xs  (thread: 16 c x 2 cols) ----
    #pragma unroll 2
    for (int n = 0; n < TILE; ++n) {
      const float xv0 = xs[n][cl];
      const float xv1 = xs[n][cl + 128];
      float sv[16];
      *reinterpret_cast<float4*>(&sv[0])  = *reinterpret_cast<const float4*>(&st[n][h * 16]);
      *reinterpret_cast<float4*>(&sv[4])  = *reinterpret_cast<const float4*>(&st[n][h * 16 + 4]);
      *reinterpret_cast<float4*>(&sv[8])  = *reinterpret_cast<const float4*>(&st[n][h * 16 + 8]);
      *reinterpret_cast<float4*>(&sv[12]) = *reinterpret_cast<const float4*>(&st[n][h * 16 + 12]);
      #pragma unroll
      for (int j = 0; j < 16; ++j) {
        macc0[j] += sv[j] * xv0;
        macc1[j] += sv[j] * xv1;
      }
    }
    // ---- SS += st^T @ st  (2x2 block per thread, 225 threads) ----
    if (t < 225) {
      #pragma unroll 4
      for (int n = 0; n < TILE; ++n) {
        const float a0 = st[n][sc1], a1 = st[n][sc1 + 1];
        const float b0 = st[n][sc2], b1 = st[n][sc2 + 1];
        ssa0 += a0 * b0; ssa1 += a0 * b1; ssa2 += a1 * b0; ssa3 += a1 * b1;
      }
    }
    if (t < C_CL) {
      #pragma unroll 4
      for (int n = 0; n < TILE; ++n) csa += st[n][t];
    }
  }
  // ---- flush per-block partials ----
  #pragma unroll
  for (int j = 0; j < 16; ++j) {
    const int c = h * 16 + j;
    if (c < C_CL) {
      atomicAdd(&ws[WS_M + c * 256 + cl], macc0[j]);
      atomicAdd(&ws[WS_M + c * 256 + cl + 128], macc1[j]);
    }
  }
  if (t < 225) {
    atomicAdd(&ws[WS_SS + sc1 * C_CL + sc2], ssa0);
    atomicAdd(&ws[WS_SS + sc1 * C_CL + sc2 + 1], ssa1);
    atomicAdd(&ws[WS_SS + (sc1 + 1) * C_CL + sc2], ssa2);
    atomicAdd(&ws[WS_SS + (sc1 + 1) * C_CL + sc2 + 1], ssa3);
  }
  if (t < C_CL) atomicAdd(&ws[WS_CS + t], csa);
}

// ---------------------------------------------------------------------------
// cut = sum_e dot(S[row_e], S[col_e])   (adj_new is all-positive => mask=ones)
__global__ __launch_bounds__(256)
void k_edges(const int* __restrict__ ei, const int E,
             const float* __restrict__ S, float* __restrict__ ws) {
  const int* __restrict__ row = ei;
  const int* __restrict__ col = ei + E;
  float acc = 0.f;
  for (int e = blockIdx.x * 256 + threadIdx.x; e < E; e += gridDim.x * 256) {
    const int r = row[e], c = col[e];
    const float2* pr = reinterpret_cast<const float2*>(S + (size_t)r * C_CL);
    const float2* pc = reinterpret_cast<const float2*>(S + (size_t)c * C_CL);
    float d = 0.f;
    #pragma unroll
    for (int k = 0; k < 15; ++k) {
      const float2 a = pr[k], b = pc[k];
      d += a.x * b.x + a.y * b.y;
    }
    acc += d;
  }
  #pragma unroll
  for (int m = 32; m >= 1; m >>= 1) acc += __shfl_xor(acc, m, 64);
  __shared__ float wsum[4];
  if ((threadIdx.x & 63) == 0) wsum[threadIdx.x >> 6] = acc;
  __syncthreads();
  if (threadIdx.x == 0)
    atomicAdd(&ws[WS_CUT], wsum[0] + wsum[1] + wsum[2] + wsum[3]);
}

// ---------------------------------------------------------------------------
// Z = M @ W_proj + colsum(S) (x) b_proj
__global__ __launch_bounds__(256)
void k_z(const float* __restrict__ ws, const float* __restrict__ Wp,
         const float* __restrict__ bp, float* __restrict__ out) {
  const int r = blockIdx.x, t = threadIdx.x;
  const float* m = ws + WS_M + r * 256;
  float acc = ws[WS_CS + r] * bp[t];
  #pragma unroll 8
  for (int k = 0; k < 256; ++k) acc += m[k] * Wp[(size_t)k * 256 + t];
  out[OUT_Z + r * 256 + t] = acc;
}

// ---------------------------------------------------------------------------
// Shapley layer with mask=ones, n=30: h = relu((in + colsum(in)/30) @ W)
__global__ __launch_bounds__(256)
void k_shlayer(const float* __restrict__ in, const float* __restrict__ W,
               float* __restrict__ outp) {
  __shared__ float sh[256];
  const int r = blockIdx.x, t = threadIdx.x;
  float cs = 0.f;
  #pragma unroll
  for (int i = 0; i < C_CL; ++i) cs += in[i * 256 + t];
  sh[t] = in[r * 256 + t] + (1.f / 30.f) * cs;
  __syncthreads();
  float acc = 0.f;
  #pragma unroll 8
  for (int k = 0; k < 256; ++k) acc += sh[k] * W[(size_t)k * 256 + t];
  outp[r * 256 + t] = fmaxf(acc, 0.f);
}

// ---------------------------------------------------------------------------
// out = h2 @ W_out + b_out ; block 30: mincut + ortho scalars
__global__ __launch_bounds__(64)
void k_out(const float* __restrict__ ws, const float* __restrict__ Wo,
           const float* __restrict__ bo, float* __restrict__ out,
           const float vol) {
  const int r = blockIdx.x, t = threadIdx.x;
  if (r < C_CL) {
    const float* hrow = ws + WS_H2 + r * 256;
    float acc = bo[t];
    #pragma unroll 8
    for (int k = 0; k < 256; ++k) acc += hrow[k] * Wo[k * 64 + t];
    out[OUT_MAT + r * 64 + t] = acc;
  } else {
    float s = 0.f;
    for (int i = t; i < C_CL * C_CL; i += 64) {
      const float d = ws[WS_SS + i] - ((i / C_CL == i % C_CL) ? 1.f : 0.f);
      s += d * d;
    }
    #pragma unroll
    for (int m = 32; m >= 1; m >>= 1) s += __shfl_xor(s, m, 64);
    if (t == 0) {
      out[OUT_OR] = sqrtf(s);
      out[OUT_MC] = -ws[WS_CUT] / (vol + 1e-9f);
    }
  }
}

// ---------------------------------------------------------------------------
extern "C" void kernel_launch(void* const* d_in, const int* in_sizes, int n_in,
                              void* d_out, int out_size, void* d_ws, size_t ws_size,
                              hipStream_t stream) {
  (void)n_in; (void)out_size; (void)ws_size;
  const float* x  = (const float*)d_in[0];
  const int*   ei = (const int*)d_in[1];
  const float* Wa = (const float*)d_in[2];
  const float* ba = (const float*)d_in[3];
  const float* Wp = (const float*)d_in[4];
  const float* bp = (const float*)d_in[5];
  const float* W1 = (const float*)d_in[6];
  const float* W2 = (const float*)d_in[7];
  const float* Wo = (const float*)d_in[8];
  const float* bo = (const float*)d_in[9];
  float* out = (float*)d_out;
  float* ws  = (float*)d_ws;
  const int E = in_sizes[1] / 2;

  k_prep<<<33, 256, 0, stream>>>(Wa, ws);
  k_assign<<<768, 256, 0, stream>>>(x, ba, out + OUT_S, ws);
  k_edges<<<2048, 256, 0, stream>>>(ei, E, out + OUT_S, ws);
  k_z<<<C_CL, 256, 0, stream>>>(ws, Wp, bp, out);
  k_shlayer<<<C_CL, 256, 0, stream>>>(out + OUT_Z, W1, ws + WS_H1);
  k_shlayer<<<C_CL, 256, 0, stream>>>(ws + WS_H1, W2, ws + WS_H2);
  k_out<<<C_CL + 1, 64, 0, stream>>>(ws, Wo, bo, out, (float)E);
}